// Round 1
// baseline (5913.949 us; speedup 1.0000x reference)
//
#include <hip/hip_runtime.h>
#include <hip/hip_bf16.h>

typedef __hip_bfloat16 bf16;
typedef short s8v __attribute__((ext_vector_type(8)));
typedef float f4v __attribute__((ext_vector_type(4)));

__device__ __forceinline__ bf16 f2bf(float x) { return __float2bfloat16(x); }

// ---------- transpose + cast weights: w[K][N] (fp32) -> wt[N][K] (bf16) ----------
__global__ void transpose_cast(const float* __restrict__ w, bf16* __restrict__ wt, int K, int N) {
    int i = blockIdx.x * blockDim.x + threadIdx.x;
    if (i >= K * N) return;
    int n = i / K, k = i - n * K;
    wt[i] = f2bf(w[k * N + n]);
}

// ---------- LayerNorm (wave per row). PERM=1: fused roll(-3)+window partition ----------
template<int PERM>
__global__ void ln_kernel(const float* __restrict__ x, const float* __restrict__ g,
                          const float* __restrict__ bta, bf16* __restrict__ out) {
    int m = blockIdx.x * 4 + (threadIdx.x >> 6);
    int lane = threadIdx.x & 63;
    long src;
    if (PERM) {
        int nw = m / 49, l = m - nw * 49;
        int b = nw >> 6, w = nw & 63;
        int wh = w >> 3, ww = w & 7;
        int i = l / 7, j = l - i * 7;
        int sh = wh * 7 + i + 3; if (sh >= 56) sh -= 56;
        int sw = ww * 7 + j + 3; if (sw >= 56) sw -= 56;
        src = ((long)(b * 3136 + sh * 56 + sw)) * 384;
    } else {
        src = (long)m * 384;
    }
    float v[6];
    float s1 = 0.f, s2 = 0.f;
#pragma unroll
    for (int p = 0; p < 6; ++p) {
        v[p] = x[src + lane + p * 64];
        s1 += v[p]; s2 += v[p] * v[p];
    }
#pragma unroll
    for (int off = 1; off < 64; off <<= 1) {
        s1 += __shfl_xor(s1, off);
        s2 += __shfl_xor(s2, off);
    }
    float mu = s1 * (1.0f / 384.0f);
    float var = s2 * (1.0f / 384.0f) - mu * mu;
    float rs = rsqrtf(var + 1e-5f);
    long dst = (long)m * 384;
#pragma unroll
    for (int p = 0; p < 6; ++p) {
        int c = lane + p * 64;
        out[dst + c] = f2bf((v[p] - mu) * rs * g[c] + bta[c]);
    }
}

// ---------- 128x128-tile bf16 MFMA GEMM with fused epilogues ----------
// A [M][K] bf16 row-major, BT [N][K] bf16 row-major (i.e. B transposed). M%128==0, N%128==0, K%64==0.
// EPI 0: qkv scatter  1: proj + window-reverse + roll + residual  2: +bias,GELU->bf16  3: +bias + in-place add fp32
template<int EPI>
__global__ void gemm_bf16(const bf16* __restrict__ A, const bf16* __restrict__ BT,
                          const float* __restrict__ bias, int K,
                          bf16* __restrict__ ob0, bf16* __restrict__ ob1, bf16* __restrict__ ob2,
                          const float* __restrict__ aux, float* __restrict__ of) {
    __shared__ bf16 As[128][72];
    __shared__ bf16 Bs[128][72];
    const int t = threadIdx.x;
    const int m0 = blockIdx.y * 128, n0 = blockIdx.x * 128;
    const int row = t >> 1, halfo = (t & 1) * 32;   // element offset within 64-wide k-tile
    const uint4* agv = (const uint4*)(A + (long)(m0 + row) * K + halfo);
    const uint4* bgv = (const uint4*)(BT + (long)(n0 + row) * K + halfo);
    const int nk = K >> 6;
    uint4 ra[4], rb[4];
#pragma unroll
    for (int u = 0; u < 4; ++u) { ra[u] = agv[u]; rb[u] = bgv[u]; }
    f4v acc[4][4];
#pragma unroll
    for (int a_ = 0; a_ < 4; ++a_)
#pragma unroll
        for (int b_ = 0; b_ < 4; ++b_) acc[a_][b_] = (f4v){0.f, 0.f, 0.f, 0.f};
    const int wv = t >> 6, lane = t & 63, quad = lane >> 4, c16 = lane & 15;
    const int wm = (wv & 1) * 64, wn = (wv >> 1) * 64;
    for (int kt = 0; kt < nk; ++kt) {
        __syncthreads();
#pragma unroll
        for (int u = 0; u < 4; ++u) {
            *(uint4*)&As[row][halfo + u * 8] = ra[u];
            *(uint4*)&Bs[row][halfo + u * 8] = rb[u];
        }
        __syncthreads();
        if (kt + 1 < nk) {
#pragma unroll
            for (int u = 0; u < 4; ++u) { ra[u] = agv[(kt + 1) * 8 + u]; rb[u] = bgv[(kt + 1) * 8 + u]; }
        }
#pragma unroll
        for (int ks = 0; ks < 2; ++ks) {
            s8v af[4], bfr[4];
#pragma unroll
            for (int i = 0; i < 4; ++i) af[i] = *(const s8v*)&As[wm + i * 16 + c16][ks * 32 + quad * 8];
#pragma unroll
            for (int i = 0; i < 4; ++i) bfr[i] = *(const s8v*)&Bs[wn + i * 16 + c16][ks * 32 + quad * 8];
#pragma unroll
            for (int mt = 0; mt < 4; ++mt)
#pragma unroll
                for (int nt = 0; nt < 4; ++nt)
                    acc[mt][nt] = __builtin_amdgcn_mfma_f32_16x16x32_bf16(af[mt], bfr[nt], acc[mt][nt], 0, 0, 0);
        }
    }
    // epilogue: lane holds C[row = wm+mt*16+quad*4+r][col = wn+nt*16+c16]
#pragma unroll
    for (int mt = 0; mt < 4; ++mt) {
#pragma unroll
        for (int nt = 0; nt < 4; ++nt) {
#pragma unroll
            for (int r = 0; r < 4; ++r) {
                int gm = m0 + wm + mt * 16 + quad * 4 + r;
                int gn = n0 + wn + nt * 16 + c16;
                float val = acc[mt][nt][r] + bias[gn];
                if (EPI == 0) {
                    int three = gn / 384;
                    int rem = gn - three * 384;
                    int nh = rem >> 5, hd = rem & 31;
                    int nw = gm / 49, l = gm - nw * 49;
                    long idx = ((long)(nw * 12 + nh) * 49 + l) * 32 + hd;
                    bf16* dst = three == 0 ? ob0 : (three == 1 ? ob1 : ob2);
                    dst[idx] = f2bf(val);
                } else if (EPI == 1) {
                    int nw = gm / 49, l = gm - nw * 49;
                    int b = nw >> 6, w = nw & 63;
                    int wh = w >> 3, ww = w & 7;
                    int i = l / 7, j = l - i * 7;
                    int dh = wh * 7 + i + 3; if (dh >= 56) dh -= 56;
                    int dw = ww * 7 + j + 3; if (dw >= 56) dw -= 56;
                    long idx = (long)(b * 3136 + dh * 56 + dw) * 384 + gn;
                    of[idx] = aux[idx] + val;
                } else if (EPI == 2) {
                    float ge = 0.5f * val * (1.0f + erff(val * 0.70710678118654752f));
                    ob0[(long)gm * 1536 + gn] = f2bf(ge);
                } else {
                    long idx = (long)gm * 384 + gn;
                    of[idx] = of[idx] + val;
                }
            }
        }
    }
}

// ---------- windowed attention: one window-head per 256-thread block ----------
__global__ __launch_bounds__(256) void attn_kernel(const bf16* __restrict__ qb, const bf16* __restrict__ kb,
                                                   const bf16* __restrict__ vb, bf16* __restrict__ ob) {
    __shared__ bf16 Q[64][40];
    __shared__ bf16 Kl[64][40];
    __shared__ bf16 Vt[32][72];
    __shared__ bf16 P[64][72];
    const int whid = blockIdx.x;
    const int n = whid / 12, nh = whid - n * 12;
    const int w = n & 63, whh = w >> 3, www = w & 7;
    const int t = threadIdx.x;
    const bf16* qp = qb + (long)whid * 1568;
    const bf16* kp = kb + (long)whid * 1568;
    const bf16* vp = vb + (long)whid * 1568;
    // zero pad rows 49..63 of Q and K
    for (int i = t; i < 1200; i += 256) {
        int which = i >= 600; int ii = i - which * 600;
        int r = ii / 40, c = ii - r * 40;
        (which ? Kl : Q)[49 + r][c] = f2bf(0.f);
    }
    // zero Vt pad cols 49..71
    for (int i = t; i < 32 * 23; i += 256) {
        int r = i / 23, c = i - r * 23;
        Vt[r][49 + c] = f2bf(0.f);
    }
    // stage Q, K (49x32 each, 196 16B-chunks each)
    for (int ch = t; ch < 392; ch += 256) {
        int which = ch >= 196; int cc = ch - which * 196;
        int r = cc >> 2, c8 = (cc & 3) * 8;
        s8v val = *(const s8v*)((which ? kp : qp) + cc * 8);
        *(s8v*)&(which ? Kl : Q)[r][c8] = val;
    }
    // stage V transposed: Vt[hd][l]
    for (int ch = t; ch < 196; ch += 256) {
        int l = ch >> 2, hd0 = (ch & 3) * 8;
        const bf16* src = vp + ch * 8;
#pragma unroll
        for (int u = 0; u < 8; ++u) Vt[hd0 + u][l] = src[u];
    }
    __syncthreads();
    const int wv = t >> 6, lane = t & 63, quad = lane >> 4, c16 = lane & 15;
    // S = Q K^T : wave wv owns row strip [wv*16, wv*16+16)
    s8v qf = *(const s8v*)&Q[wv * 16 + c16][quad * 8];
    f4v accS[4];
#pragma unroll
    for (int nt = 0; nt < 4; ++nt) {
        s8v kf = *(const s8v*)&Kl[nt * 16 + c16][quad * 8];
        f4v z = (f4v){0.f, 0.f, 0.f, 0.f};
        accS[nt] = __builtin_amdgcn_mfma_f32_16x16x32_bf16(qf, kf, z, 0, 0, 0);
    }
    // shifted-window mask labels (zones only nontrivial in last window row/col)
    int lab2[4]; bool valid2[4];
#pragma unroll
    for (int nt = 0; nt < 4; ++nt) {
        int l2 = nt * 16 + c16;
        int i = l2 / 7, j = l2 - i * 7;
        int rz = (whh == 7) ? ((i < 4) ? 1 : 2) : 0;
        int cz = (www == 7) ? ((j < 4) ? 1 : 2) : 0;
        lab2[nt] = rz * 3 + cz;
        valid2[nt] = l2 < 49;
    }
    const float scale = 0.17677669529663687f;
#pragma unroll
    for (int r = 0; r < 4; ++r) {
        int l1 = wv * 16 + quad * 4 + r;
        int i1 = l1 / 7, j1 = l1 - i1 * 7;
        int rz1 = (whh == 7) ? ((i1 < 4) ? 1 : 2) : 0;
        int cz1 = (www == 7) ? ((j1 < 4) ? 1 : 2) : 0;
        int lab1 = rz1 * 3 + cz1;
        float sv[4];
#pragma unroll
        for (int nt = 0; nt < 4; ++nt)
            sv[nt] = valid2[nt] ? (accS[nt][r] * scale + (lab1 != lab2[nt] ? -100.f : 0.f)) : -1e30f;
        float mx = fmaxf(fmaxf(sv[0], sv[1]), fmaxf(sv[2], sv[3]));
#pragma unroll
        for (int off = 1; off < 16; off <<= 1) mx = fmaxf(mx, __shfl_xor(mx, off));
        float s = 0.f, p[4];
#pragma unroll
        for (int nt = 0; nt < 4; ++nt) { p[nt] = __expf(sv[nt] - mx); s += p[nt]; }
#pragma unroll
        for (int off = 1; off < 16; off <<= 1) s += __shfl_xor(s, off);
        float inv = 1.0f / s;
#pragma unroll
        for (int nt = 0; nt < 4; ++nt)
            P[wv * 16 + quad * 4 + r][nt * 16 + c16] = f2bf(p[nt] * inv);
    }
    __syncthreads();
    // O = P V : A-frag from P rows of own strip, B-frag from transposed V
    f4v accO[2];
#pragma unroll
    for (int i = 0; i < 2; ++i) accO[i] = (f4v){0.f, 0.f, 0.f, 0.f};
#pragma unroll
    for (int kk = 0; kk < 2; ++kk) {
        s8v pf = *(const s8v*)&P[wv * 16 + c16][kk * 32 + quad * 8];
#pragma unroll
        for (int nt = 0; nt < 2; ++nt) {
            s8v vf = *(const s8v*)&Vt[nt * 16 + c16][kk * 32 + quad * 8];
            accO[nt] = __builtin_amdgcn_mfma_f32_16x16x32_bf16(pf, vf, accO[nt], 0, 0, 0);
        }
    }
#pragma unroll
    for (int nt = 0; nt < 2; ++nt)
#pragma unroll
        for (int r = 0; r < 4; ++r) {
            int l = wv * 16 + quad * 4 + r;
            if (l < 49)
                ob[((long)(n * 49 + l)) * 384 + nh * 32 + nt * 16 + c16] = f2bf(accO[nt][r]);
        }
}

extern "C" void kernel_launch(void* const* d_in, const int* in_sizes, int n_in,
                              void* d_out, int out_size, void* d_ws, size_t ws_size,
                              hipStream_t stream) {
    (void)in_sizes; (void)n_in; (void)out_size; (void)ws_size;
    const float* x      = (const float*)d_in[0];
    const float* g1     = (const float*)d_in[1];
    const float* bn1    = (const float*)d_in[2];
    const float* w_qkv  = (const float*)d_in[3];
    const float* b_qkv  = (const float*)d_in[4];
    const float* w_proj = (const float*)d_in[5];
    const float* b_proj = (const float*)d_in[6];
    const float* g2     = (const float*)d_in[7];
    const float* bn2    = (const float*)d_in[8];
    const float* w_mlp1 = (const float*)d_in[9];
    const float* b_mlp1 = (const float*)d_in[10];
    const float* w_mlp2 = (const float*)d_in[11];
    const float* b_mlp2 = (const float*)d_in[12];
    float* out = (float*)d_out;
    char* ws = (char*)d_ws;

    const long M = 200704;  // 64*56*56 rows
    // workspace layout (bytes):
    bf16* slot0  = (bf16*)ws;                                   // 616,562,688 (winA / attnO / mlp1-out)
    bf16* qbuf   = (bf16*)(ws + 616562688L);                    // 154,140,672
    bf16* kbuf   = (bf16*)(ws + 616562688L + 154140672L);
    bf16* vbuf   = (bf16*)(ws + 616562688L + 2 * 154140672L);
    bf16* wqkvT  = (bf16*)(ws + 616562688L + 3 * 154140672L);   // 1152*384
    bf16* wprojT = wqkvT + 442368;                              // 384*384
    bf16* wmlp1T = wprojT + 147456;                             // 1536*384
    bf16* wmlp2T = wmlp1T + 589824;                             // 384*1536
    bf16* winA = slot0;
    bf16* obuf = slot0;
    bf16* m1   = slot0;
    bf16* h2   = qbuf;   // reuse q slot after attention

    transpose_cast<<<442368 / 256, 256, 0, stream>>>(w_qkv, wqkvT, 384, 1152);
    transpose_cast<<<147456 / 256, 256, 0, stream>>>(w_proj, wprojT, 384, 384);
    transpose_cast<<<589824 / 256, 256, 0, stream>>>(w_mlp1, wmlp1T, 384, 1536);
    transpose_cast<<<589824 / 256, 256, 0, stream>>>(w_mlp2, wmlp2T, 1536, 384);

    // LN1 + roll + window partition -> winA (bf16, windowed row order)
    ln_kernel<1><<<M / 4, 256, 0, stream>>>(x, g1, bn1, winA);
    // QKV projection, scatter to per-window-head q/k/v
    gemm_bf16<0><<<dim3(9, 1568), 256, 0, stream>>>(winA, wqkvT, b_qkv, 384, qbuf, kbuf, vbuf, nullptr, nullptr);
    // windowed attention
    attn_kernel<<<49152, 256, 0, stream>>>(qbuf, kbuf, vbuf, obuf);
    // proj + window reverse + roll + residual -> x2 stored in d_out
    gemm_bf16<1><<<dim3(3, 1568), 256, 0, stream>>>(obuf, wprojT, b_proj, 384, nullptr, nullptr, nullptr, x, out);
    // LN2 -> h2 (bf16)
    ln_kernel<0><<<M / 4, 256, 0, stream>>>(out, g2, bn2, h2);
    // MLP1 + GELU -> m1 (bf16)
    gemm_bf16<2><<<dim3(12, 1568), 256, 0, stream>>>(h2, wmlp1T, b_mlp1, 384, m1, nullptr, nullptr, nullptr, nullptr);
    // MLP2 + residual, in-place on d_out
    gemm_bf16<3><<<dim3(3, 1568), 256, 0, stream>>>(m1, wmlp2T, b_mlp2, 1536, nullptr, nullptr, nullptr, nullptr, out);
}

// Round 2
// 4287.120 us; speedup vs baseline: 1.3795x; 1.3795x over previous
//
#include <hip/hip_runtime.h>
#include <hip/hip_bf16.h>

typedef __hip_bfloat16 bf16;
typedef short s8v __attribute__((ext_vector_type(8)));
typedef float f4v __attribute__((ext_vector_type(4)));

__device__ __forceinline__ bf16 f2bf(float x) { return __float2bfloat16(x); }

struct bf4 { bf16 a, b, c, d; };

// ---------- transpose + cast weights: w[K][N] (fp32) -> wt[N][K] (bf16) ----------
__global__ void transpose_cast(const float* __restrict__ w, bf16* __restrict__ wt, int K, int N) {
    int i = blockIdx.x * blockDim.x + threadIdx.x;
    if (i >= K * N) return;
    int n = i / K, k = i - n * K;
    wt[i] = f2bf(w[k * N + n]);
}

// ---------- LayerNorm (wave per row). PERM=1: fused roll(-3)+window partition ----------
template<int PERM>
__global__ void ln_kernel(const float* __restrict__ x, const float* __restrict__ g,
                          const float* __restrict__ bta, bf16* __restrict__ out) {
    int m = blockIdx.x * 4 + (threadIdx.x >> 6);
    int lane = threadIdx.x & 63;
    long src;
    if (PERM) {
        int nw = m / 49, l = m - nw * 49;
        int b = nw >> 6, w = nw & 63;
        int wh = w >> 3, ww = w & 7;
        int i = l / 7, j = l - i * 7;
        int sh = wh * 7 + i + 3; if (sh >= 56) sh -= 56;
        int sw = ww * 7 + j + 3; if (sw >= 56) sw -= 56;
        src = ((long)(b * 3136 + sh * 56 + sw)) * 384;
    } else {
        src = (long)m * 384;
    }
    float v[6];
    float s1 = 0.f, s2 = 0.f;
#pragma unroll
    for (int p = 0; p < 6; ++p) {
        v[p] = x[src + lane + p * 64];
        s1 += v[p]; s2 += v[p] * v[p];
    }
#pragma unroll
    for (int off = 1; off < 64; off <<= 1) {
        s1 += __shfl_xor(s1, off);
        s2 += __shfl_xor(s2, off);
    }
    float mu = s1 * (1.0f / 384.0f);
    float var = s2 * (1.0f / 384.0f) - mu * mu;
    float rs = rsqrtf(var + 1e-5f);
    long dst = (long)m * 384;
#pragma unroll
    for (int p = 0; p < 6; ++p) {
        int c = lane + p * 64;
        out[dst + c] = f2bf((v[p] - mu) * rs * g[c] + bta[c]);
    }
}

// ---------- 128x128-tile bf16 MFMA GEMM with fused epilogues ----------
// EPI 0: qkv scatter  1: proj + window-reverse + roll + residual
template<int EPI>
__global__ void gemm_bf16(const bf16* __restrict__ A, const bf16* __restrict__ BT,
                          const float* __restrict__ bias, int K,
                          bf16* __restrict__ ob0, bf16* __restrict__ ob1, bf16* __restrict__ ob2,
                          const float* __restrict__ aux, float* __restrict__ of) {
    __shared__ bf16 As[128][72];
    __shared__ bf16 Bs[128][72];
    const int t = threadIdx.x;
    const int m0 = blockIdx.y * 128, n0 = blockIdx.x * 128;
    const int row = t >> 1, halfo = (t & 1) * 32;
    const uint4* agv = (const uint4*)(A + (long)(m0 + row) * K + halfo);
    const uint4* bgv = (const uint4*)(BT + (long)(n0 + row) * K + halfo);
    const int nk = K >> 6;
    uint4 ra[4], rb[4];
#pragma unroll
    for (int u = 0; u < 4; ++u) { ra[u] = agv[u]; rb[u] = bgv[u]; }
    f4v acc[4][4];
#pragma unroll
    for (int a_ = 0; a_ < 4; ++a_)
#pragma unroll
        for (int b_ = 0; b_ < 4; ++b_) acc[a_][b_] = (f4v){0.f, 0.f, 0.f, 0.f};
    const int wv = t >> 6, lane = t & 63, quad = lane >> 4, c16 = lane & 15;
    const int wm = (wv & 1) * 64, wn = (wv >> 1) * 64;
    for (int kt = 0; kt < nk; ++kt) {
        __syncthreads();
#pragma unroll
        for (int u = 0; u < 4; ++u) {
            *(uint4*)&As[row][halfo + u * 8] = ra[u];
            *(uint4*)&Bs[row][halfo + u * 8] = rb[u];
        }
        __syncthreads();
        if (kt + 1 < nk) {
#pragma unroll
            for (int u = 0; u < 4; ++u) { ra[u] = agv[(kt + 1) * 8 + u]; rb[u] = bgv[(kt + 1) * 8 + u]; }
        }
#pragma unroll
        for (int ks = 0; ks < 2; ++ks) {
            s8v af[4], bfr[4];
#pragma unroll
            for (int i = 0; i < 4; ++i) af[i] = *(const s8v*)&As[wm + i * 16 + c16][ks * 32 + quad * 8];
#pragma unroll
            for (int i = 0; i < 4; ++i) bfr[i] = *(const s8v*)&Bs[wn + i * 16 + c16][ks * 32 + quad * 8];
#pragma unroll
            for (int mt = 0; mt < 4; ++mt)
#pragma unroll
                for (int nt = 0; nt < 4; ++nt)
                    acc[mt][nt] = __builtin_amdgcn_mfma_f32_16x16x32_bf16(af[mt], bfr[nt], acc[mt][nt], 0, 0, 0);
        }
    }
#pragma unroll
    for (int mt = 0; mt < 4; ++mt) {
#pragma unroll
        for (int nt = 0; nt < 4; ++nt) {
#pragma unroll
            for (int r = 0; r < 4; ++r) {
                int gm = m0 + wm + mt * 16 + quad * 4 + r;
                int gn = n0 + wn + nt * 16 + c16;
                float val = acc[mt][nt][r] + bias[gn];
                if (EPI == 0) {
                    int three = gn / 384;
                    int rem = gn - three * 384;
                    int nh = rem >> 5, hd = rem & 31;
                    int nw = gm / 49, l = gm - nw * 49;
                    long idx = ((long)(nw * 12 + nh) * 49 + l) * 32 + hd;
                    bf16* dst = three == 0 ? ob0 : (three == 1 ? ob1 : ob2);
                    dst[idx] = f2bf(val);
                } else {
                    int nw = gm / 49, l = gm - nw * 49;
                    int b = nw >> 6, w = nw & 63;
                    int wh = w >> 3, ww = w & 7;
                    int i = l / 7, j = l - i * 7;
                    int dh = wh * 7 + i + 3; if (dh >= 56) dh -= 56;
                    int dw = ww * 7 + j + 3; if (dw >= 56) dw -= 56;
                    long idx = (long)(b * 3136 + dh * 56 + dw) * 384 + gn;
                    of[idx] = aux[idx] + val;
                }
            }
        }
    }
}

// ---------- windowed attention: one window-head per 256-thread block ----------
__global__ __launch_bounds__(256) void attn_kernel(const bf16* __restrict__ qb, const bf16* __restrict__ kb,
                                                   const bf16* __restrict__ vb, bf16* __restrict__ ob) {
    __shared__ bf16 Q[64][40];
    __shared__ bf16 Kl[64][40];
    __shared__ bf16 Vt[32][72];
    __shared__ bf16 P[64][72];
    const int whid = blockIdx.x;
    const int n = whid / 12, nh = whid - n * 12;
    const int w = n & 63, whh = w >> 3, www = w & 7;
    const int t = threadIdx.x;
    const bf16* qp = qb + (long)whid * 1568;
    const bf16* kp = kb + (long)whid * 1568;
    const bf16* vp = vb + (long)whid * 1568;
    for (int i = t; i < 1200; i += 256) {
        int which = i >= 600; int ii = i - which * 600;
        int r = ii / 40, c = ii - r * 40;
        (which ? Kl : Q)[49 + r][c] = f2bf(0.f);
    }
    for (int i = t; i < 32 * 23; i += 256) {
        int r = i / 23, c = i - r * 23;
        Vt[r][49 + c] = f2bf(0.f);
    }
    for (int ch = t; ch < 392; ch += 256) {
        int which = ch >= 196; int cc = ch - which * 196;
        int r = cc >> 2, c8 = (cc & 3) * 8;
        s8v val = *(const s8v*)((which ? kp : qp) + cc * 8);
        *(s8v*)&(which ? Kl : Q)[r][c8] = val;
    }
    for (int ch = t; ch < 196; ch += 256) {
        int l = ch >> 2, hd0 = (ch & 3) * 8;
        const bf16* src = vp + ch * 8;
#pragma unroll
        for (int u = 0; u < 8; ++u) Vt[hd0 + u][l] = src[u];
    }
    __syncthreads();
    const int wv = t >> 6, lane = t & 63, quad = lane >> 4, c16 = lane & 15;
    s8v qf = *(const s8v*)&Q[wv * 16 + c16][quad * 8];
    f4v accS[4];
#pragma unroll
    for (int nt = 0; nt < 4; ++nt) {
        s8v kf = *(const s8v*)&Kl[nt * 16 + c16][quad * 8];
        f4v z = (f4v){0.f, 0.f, 0.f, 0.f};
        accS[nt] = __builtin_amdgcn_mfma_f32_16x16x32_bf16(qf, kf, z, 0, 0, 0);
    }
    int lab2[4]; bool valid2[4];
#pragma unroll
    for (int nt = 0; nt < 4; ++nt) {
        int l2 = nt * 16 + c16;
        int i = l2 / 7, j = l2 - i * 7;
        int rz = (whh == 7) ? ((i < 4) ? 1 : 2) : 0;
        int cz = (www == 7) ? ((j < 4) ? 1 : 2) : 0;
        lab2[nt] = rz * 3 + cz;
        valid2[nt] = l2 < 49;
    }
    const float scale = 0.17677669529663687f;
#pragma unroll
    for (int r = 0; r < 4; ++r) {
        int l1 = wv * 16 + quad * 4 + r;
        int i1 = l1 / 7, j1 = l1 - i1 * 7;
        int rz1 = (whh == 7) ? ((i1 < 4) ? 1 : 2) : 0;
        int cz1 = (www == 7) ? ((j1 < 4) ? 1 : 2) : 0;
        int lab1 = rz1 * 3 + cz1;
        float sv[4];
#pragma unroll
        for (int nt = 0; nt < 4; ++nt)
            sv[nt] = valid2[nt] ? (accS[nt][r] * scale + (lab1 != lab2[nt] ? -100.f : 0.f)) : -1e30f;
        float mx = fmaxf(fmaxf(sv[0], sv[1]), fmaxf(sv[2], sv[3]));
#pragma unroll
        for (int off = 1; off < 16; off <<= 1) mx = fmaxf(mx, __shfl_xor(mx, off));
        float s = 0.f, p[4];
#pragma unroll
        for (int nt = 0; nt < 4; ++nt) { p[nt] = __expf(sv[nt] - mx); s += p[nt]; }
#pragma unroll
        for (int off = 1; off < 16; off <<= 1) s += __shfl_xor(s, off);
        float inv = 1.0f / s;
#pragma unroll
        for (int nt = 0; nt < 4; ++nt)
            P[wv * 16 + quad * 4 + r][nt * 16 + c16] = f2bf(p[nt] * inv);
    }
    __syncthreads();
    f4v accO[2];
#pragma unroll
    for (int i = 0; i < 2; ++i) accO[i] = (f4v){0.f, 0.f, 0.f, 0.f};
#pragma unroll
    for (int kk = 0; kk < 2; ++kk) {
        s8v pf = *(const s8v*)&P[wv * 16 + c16][kk * 32 + quad * 8];
#pragma unroll
        for (int nt = 0; nt < 2; ++nt) {
            s8v vf = *(const s8v*)&Vt[nt * 16 + c16][kk * 32 + quad * 8];
            accO[nt] = __builtin_amdgcn_mfma_f32_16x16x32_bf16(pf, vf, accO[nt], 0, 0, 0);
        }
    }
#pragma unroll
    for (int nt = 0; nt < 2; ++nt)
#pragma unroll
        for (int r = 0; r < 4; ++r) {
            int l = wv * 16 + quad * 4 + r;
            if (l < 49)
                ob[((long)(n * 49 + l)) * 384 + nh * 32 + nt * 16 + c16] = f2bf(accO[nt][r]);
        }
}

// ---------- fused LN2 + MLP1 + GELU + MLP2 + residual (in-place on out) ----------
// Block: 64 rows, 256 threads (4 waves). Weights read directly from global (L2-resident).
__global__ __launch_bounds__(256) void ln_mlp_kernel(const float* __restrict__ g2, const float* __restrict__ bn2,
                                                     const bf16* __restrict__ w1T, const float* __restrict__ b1,
                                                     const bf16* __restrict__ w2T, const float* __restrict__ b2,
                                                     float* __restrict__ out) {
    __shared__ bf16 As[64][392];   // LN output tile, padded (stride ≡ 4 banks → 2-way max)
    __shared__ bf16 Tc[64][136];   // GELU(m1) chunk
    __shared__ float gb[768];      // g2 | bn2
    const int t = threadIdx.x;
    const long m0 = (long)blockIdx.x * 64;
    for (int i = t; i < 768; i += 256) gb[i] = (i < 384) ? g2[i] : bn2[i - 384];

    // ---- LN2 on own 64 rows: thread = (row, quarter), 96 cols each ----
    {
        const int row = t >> 2, q = t & 3;
        const float4* xr = (const float4*)(out + (m0 + row) * 384 + q * 96);
        float4 v[24];
        float s1 = 0.f, s2 = 0.f;
#pragma unroll
        for (int i = 0; i < 24; ++i) {
            v[i] = xr[i];
            s1 += v[i].x + v[i].y + v[i].z + v[i].w;
            s2 += v[i].x * v[i].x + v[i].y * v[i].y + v[i].z * v[i].z + v[i].w * v[i].w;
        }
        s1 += __shfl_xor(s1, 1); s1 += __shfl_xor(s1, 2);
        s2 += __shfl_xor(s2, 1); s2 += __shfl_xor(s2, 2);
        float mu = s1 * (1.0f / 384.0f);
        float rs = rsqrtf(s2 * (1.0f / 384.0f) - mu * mu + 1e-5f);
        __syncthreads();   // gb ready
#pragma unroll
        for (int i = 0; i < 24; ++i) {
            int c = q * 96 + i * 4;
            bf4 pk;
            pk.a = f2bf((v[i].x - mu) * rs * gb[c]     + gb[384 + c]);
            pk.b = f2bf((v[i].y - mu) * rs * gb[c + 1] + gb[385 + c]);
            pk.c = f2bf((v[i].z - mu) * rs * gb[c + 2] + gb[386 + c]);
            pk.d = f2bf((v[i].w - mu) * rs * gb[c + 3] + gb[387 + c]);
            *(bf4*)&As[row][c] = pk;
        }
    }
    __syncthreads();   // As ready

    const int wv = t >> 6, lane = t & 63, quad = lane >> 4, c16 = lane & 15;
    f4v acc2[4][6];
#pragma unroll
    for (int a = 0; a < 4; ++a)
#pragma unroll
        for (int b = 0; b < 6; ++b) acc2[a][b] = (f4v){0.f, 0.f, 0.f, 0.f};

    for (int c = 0; c < 12; ++c) {
        // ---- stage 1: S = A @ w1 chunk (this wave: 32 cols of the 128-chunk) ----
        f4v sacc[4][2];
#pragma unroll
        for (int a = 0; a < 4; ++a) { sacc[a][0] = (f4v){0.f,0.f,0.f,0.f}; sacc[a][1] = (f4v){0.f,0.f,0.f,0.f}; }
        const bf16* w1p = w1T + (long)(c * 128 + wv * 32 + c16) * 384 + quad * 8;
#pragma unroll 3
        for (int ks = 0; ks < 12; ++ks) {
            s8v af[4], bw[2];
#pragma unroll
            for (int mt = 0; mt < 4; ++mt) af[mt] = *(const s8v*)&As[mt * 16 + c16][ks * 32 + quad * 8];
            bw[0] = *(const s8v*)(w1p + ks * 32);
            bw[1] = *(const s8v*)(w1p + 16 * 384 + ks * 32);
#pragma unroll
            for (int mt = 0; mt < 4; ++mt) {
                sacc[mt][0] = __builtin_amdgcn_mfma_f32_16x16x32_bf16(af[mt], bw[0], sacc[mt][0], 0, 0, 0);
                sacc[mt][1] = __builtin_amdgcn_mfma_f32_16x16x32_bf16(af[mt], bw[1], sacc[mt][1], 0, 0, 0);
            }
        }
        float b1v0 = b1[c * 128 + wv * 32 + c16];
        float b1v1 = b1[c * 128 + wv * 32 + 16 + c16];
        __syncthreads();   // previous chunk's stage-2 done reading Tc
#pragma unroll
        for (int mt = 0; mt < 4; ++mt)
#pragma unroll
            for (int nt = 0; nt < 2; ++nt)
#pragma unroll
                for (int r = 0; r < 4; ++r) {
                    float val = sacc[mt][nt][r] + (nt ? b1v1 : b1v0);
                    float ge = 0.5f * val * (1.0f + erff(val * 0.70710678118654752f));
                    Tc[mt * 16 + quad * 4 + r][wv * 32 + nt * 16 + c16] = f2bf(ge);
                }
        __syncthreads();   // Tc ready
        // ---- stage 2: acc2 += Tc @ w2 chunk (this wave: 96 of 384 out cols) ----
#pragma unroll
        for (int ks = 0; ks < 4; ++ks) {
            s8v pf[4];
#pragma unroll
            for (int mt = 0; mt < 4; ++mt) pf[mt] = *(const s8v*)&Tc[mt * 16 + c16][ks * 32 + quad * 8];
#pragma unroll
            for (int j = 0; j < 6; ++j) {
                s8v wf = *(const s8v*)(w2T + (long)(wv * 96 + j * 16 + c16) * 1536 + c * 128 + ks * 32 + quad * 8);
#pragma unroll
                for (int mt = 0; mt < 4; ++mt)
                    acc2[mt][j] = __builtin_amdgcn_mfma_f32_16x16x32_bf16(pf[mt], wf, acc2[mt][j], 0, 0, 0);
            }
        }
    }
    // ---- epilogue: out += acc2 + b2 ----
#pragma unroll
    for (int j = 0; j < 6; ++j) {
        int col = wv * 96 + j * 16 + c16;
        float bb = b2[col];
#pragma unroll
        for (int mt = 0; mt < 4; ++mt)
#pragma unroll
            for (int r = 0; r < 4; ++r) {
                long idx = (m0 + mt * 16 + quad * 4 + r) * 384 + col;
                out[idx] = out[idx] + acc2[mt][j][r] + bb;
            }
    }
}

extern "C" void kernel_launch(void* const* d_in, const int* in_sizes, int n_in,
                              void* d_out, int out_size, void* d_ws, size_t ws_size,
                              hipStream_t stream) {
    (void)in_sizes; (void)n_in; (void)out_size; (void)ws_size;
    const float* x      = (const float*)d_in[0];
    const float* g1     = (const float*)d_in[1];
    const float* bn1    = (const float*)d_in[2];
    const float* w_qkv  = (const float*)d_in[3];
    const float* b_qkv  = (const float*)d_in[4];
    const float* w_proj = (const float*)d_in[5];
    const float* b_proj = (const float*)d_in[6];
    const float* g2     = (const float*)d_in[7];
    const float* bn2    = (const float*)d_in[8];
    const float* w_mlp1 = (const float*)d_in[9];
    const float* b_mlp1 = (const float*)d_in[10];
    const float* w_mlp2 = (const float*)d_in[11];
    const float* b_mlp2 = (const float*)d_in[12];
    float* out = (float*)d_out;
    char* ws = (char*)d_ws;

    const long M = 200704;
    bf16* slot0  = (bf16*)ws;                                   // winA / attnO
    bf16* qbuf   = (bf16*)(ws + 616562688L);
    bf16* kbuf   = (bf16*)(ws + 616562688L + 154140672L);
    bf16* vbuf   = (bf16*)(ws + 616562688L + 2 * 154140672L);
    bf16* wqkvT  = (bf16*)(ws + 616562688L + 3 * 154140672L);
    bf16* wprojT = wqkvT + 442368;
    bf16* wmlp1T = wprojT + 147456;
    bf16* wmlp2T = wmlp1T + 589824;
    bf16* winA = slot0;
    bf16* obuf = slot0;

    transpose_cast<<<442368 / 256, 256, 0, stream>>>(w_qkv, wqkvT, 384, 1152);
    transpose_cast<<<147456 / 256, 256, 0, stream>>>(w_proj, wprojT, 384, 384);
    transpose_cast<<<589824 / 256, 256, 0, stream>>>(w_mlp1, wmlp1T, 384, 1536);
    transpose_cast<<<589824 / 256, 256, 0, stream>>>(w_mlp2, wmlp2T, 1536, 384);

    // LN1 + roll + window partition
    ln_kernel<1><<<M / 4, 256, 0, stream>>>(x, g1, bn1, winA);
    // QKV projection, scatter to per-window-head q/k/v
    gemm_bf16<0><<<dim3(9, 1568), 256, 0, stream>>>(winA, wqkvT, b_qkv, 384, qbuf, kbuf, vbuf, nullptr, nullptr);
    // windowed attention
    attn_kernel<<<49152, 256, 0, stream>>>(qbuf, kbuf, vbuf, obuf);
    // proj + window reverse + roll + residual -> x2 in d_out
    gemm_bf16<1><<<dim3(3, 1568), 256, 0, stream>>>(obuf, wprojT, b_proj, 384, nullptr, nullptr, nullptr, x, out);
    // fused LN2 + MLP1 + GELU + MLP2 + residual, in-place on d_out
    ln_mlp_kernel<<<M / 64, 256, 0, stream>>>(g2, bn2, wmlp1T, b_mlp1, wmlp2T, b_mlp2, out);
}